// Round 11
// baseline (237.516 us; speedup 1.0000x reference)
//
#include <hip/hip_runtime.h>

// ---------------------------------------------------------------------------
// DistanceLoss pipeline on MI355X (gfx950)
//
// R4: tuple-gather factored out of embed GEMM (Y = X@Wsplit^T, 16.8 GFLOP).
// R5: contrast as per-(class,row) wave dot products.
// R9: split-K=2 GEMMs, 3-stage global_load_lds ring.
// R10: build_e2 sample-tiled; dist_fix+stats fused.
// R11: GEMM tiles 128x128 -> 128x64: grids 1024/1296 blocks (4-5/CU resident,
//      LDS 36 KB/block) to fix grid-limited latency hiding; 3 DMAs/thread/iter,
//      vmcnt(3); wave-tile 32x64 (2x4 frags, 32-VGPR acc).
//
//  1. prep: W fp32->split bf16; X bf16; zero record/msum/sq
//  2. gemm_ring grid(8,64,2):  Yz = X @ Wsplit^T (half-K partials, fp32)
//  3. build_e2: E rows (bf16) from Y0+Y1, sample-tiled; sq via atomics
//  4. gemm_ring grid(36,18,2): Pz = E @ Esup^T (half-K partials)
//  5. dist_stats: D = sqrt(...), + per-(c,i) stats for query rows
//  6. record_part(675) / record_finish(+msum)
//  7. contrast_rows / final_kernel
// ---------------------------------------------------------------------------

typedef __bf16 bf16x8 __attribute__((ext_vector_type(8)));
typedef float f32x4 __attribute__((ext_vector_type(4)));

#define NQT   3375      // 75*45 query-tuple rows
#define MROWS 4500      // 3375 query rows + 1125 support rows
#define MPAD  4608      // 36 * 128
#define LDD   1152      // padded 1125 -> 9*128
#define BK    32        // K-tile; LDS stride = 32 (UNPADDED: required by global_load_lds)

__constant__ int P0[45] = {0,0,0,0,0,0,0,0,0,
                           1,1,1,1,1,1,1,1,
                           2,2,2,2,2,2,2,
                           3,3,3,3,3,3,
                           4,4,4,4,4,
                           5,5,5,5,
                           6,6,6,
                           7,7,
                           8};
__constant__ int P1[45] = {1,2,3,4,5,6,7,8,9,
                           2,3,4,5,6,7,8,9,
                           3,4,5,6,7,8,9,
                           4,5,6,7,8,9,
                           5,6,7,8,9,
                           6,7,8,9,
                           7,8,9,
                           8,9,
                           9};

__device__ inline unsigned short f2b(float x) {
  __bf16 b = (__bf16)x;               // RNE
  return __builtin_bit_cast(unsigned short, b);
}
__device__ inline float b2f(unsigned int u16) {
  return __uint_as_float(u16 << 16);
}

// async global->LDS, 16B per lane; lds dest must be wave-uniform base + lane*16
__device__ __forceinline__ void gl_lds16(const unsigned short* g, unsigned short* l) {
  __builtin_amdgcn_global_load_lds(
      (__attribute__((address_space(1))) void*)(g),
      (__attribute__((address_space(3))) void*)(l),
      16, 0, 0);
}

// ---- 1: prep: conv W (split) + conv X + zero record/msum/sq ----------------
__global__ void prep(const float* __restrict__ W, const float* __restrict__ Q,
                     const float* __restrict__ Sp,
                     unsigned short* __restrict__ Ws, unsigned short* __restrict__ X,
                     float* __restrict__ record, float* __restrict__ msum,
                     float* __restrict__ sq) {
  int b = blockIdx.x, tid = threadIdx.x;
  if (b < 8192) {                                    // W -> split bf16
    int i = b * 256 + tid;
    int i4 = i << 2;
    int o  = i4 >> 12;
    int k  = i4 & 4095;
    int hf = k >> 11;
    int kk = k & 2047;
    float4 v = reinterpret_cast<const float4*>(W)[i];
    ushort4 u;
    u.x = f2b(v.x); u.y = f2b(v.y); u.z = f2b(v.z); u.w = f2b(v.w);
    *reinterpret_cast<ushort4*>(Ws + (size_t)(o + hf * 2048) * 2048 + kk) = u;
  } else if (b < 10240) {                            // X = bf16(Q || S), pad 0
    int i = (b - 8192) * 256 + tid;
    ushort4 u = {0, 0, 0, 0};
    if (i < 384000) {                                // 750*2048/4
      float4 v = reinterpret_cast<const float4*>(Q)[i];
      u.x = f2b(v.x); u.y = f2b(v.y); u.z = f2b(v.z); u.w = f2b(v.w);
    } else if (i < 512000) {                         // + 250*2048/4
      float4 v = reinterpret_cast<const float4*>(Sp)[i - 384000];
      u.x = f2b(v.x); u.y = f2b(v.y); u.z = f2b(v.z); u.w = f2b(v.w);
    }
    reinterpret_cast<ushort4*>(X)[i] = u;
  } else {                                           // zero record + msum + sq
    int i = (b - 10240) * 256 + tid;
    if (i < 4500) record[i] = 0.f;
    else if (i < 4505) msum[i - 4500] = 0.f;
    else if (i < 4505 + 4608) sq[i - 4505] = 0.f;
  }
}

// ---- 2/4: bf16 MFMA GEMM, C = A @ B^T, 128x64 tile, BK=32, split-K ---------
// 3-stage pipelined global_load_lds ring; chunk-XOR swizzle.
// 4 waves, wave w owns rows [w*32, w*32+32) x all 64 cols (2x4 frags).
// blockIdx.z selects K-half; raw fp32 accumulator partial stored to Pz.
__global__ __launch_bounds__(256)
void gemm_ring(const unsigned short* __restrict__ A, const unsigned short* __restrict__ B,
               int lda, int ldb, int Ksplit,
               float* __restrict__ Pout0, float* __restrict__ Pout1, int ldd) {
  __shared__ unsigned short As[3][128 * BK];   // 3 x 8 KB
  __shared__ unsigned short Bs[3][64 * BK];    // 3 x 4 KB
  const int tid  = threadIdx.x;
  const int wave = tid >> 6, lane = tid & 63;
  const int quad = lane >> 4, l16 = lane & 15;
  const int wm = wave * 32;
  const int m0 = blockIdx.x * 128, n0 = blockIdx.y * 64;
  const int kbase = blockIdx.z * Ksplit;

  f32x4 acc[2][4];
#pragma unroll
  for (int i = 0; i < 2; ++i)
#pragma unroll
    for (int j = 0; j < 4; ++j) {
      f32x4 z = {0.f, 0.f, 0.f, 0.f};
      acc[i][j] = z;
    }

  const int r0  = tid >> 2;                          // 0..63
  const int qsw = (tid & 3) ^ ((tid >> 3) & 3);      // swizzled global chunk
  const int kp0 = qsw * 8;
  const int rsw = (quad ^ ((l16 >> 1) & 3)) * 8;     // conflict-free read slot
  const unsigned short* pa0 = A + (size_t)(m0 + r0) * lda + kbase + kp0;
  const unsigned short* pa1 = A + (size_t)(m0 + r0 + 64) * lda + kbase + kp0;
  const unsigned short* pb0 = B + (size_t)(n0 + r0) * ldb + kbase + kp0;
  const int NKi = Ksplit / BK;

#define ISSUE(kk, st) do {                                   \
    gl_lds16(pa0 + (size_t)(kk) * BK, &As[st][wave * 512]);        \
    gl_lds16(pa1 + (size_t)(kk) * BK, &As[st][2048 + wave * 512]); \
    gl_lds16(pb0 + (size_t)(kk) * BK, &Bs[st][wave * 512]);        \
  } while (0)

  ISSUE(0, 0);
  ISSUE(1, 1);
  asm volatile("s_waitcnt vmcnt(3)" ::: "memory");   // tile 0 resident
  __builtin_amdgcn_s_barrier();

  int sc = 0;
  for (int k = 0; k < NKi; ++k) {
    int sn = sc + 2; if (sn >= 3) sn -= 3;
    if (k + 2 < NKi) ISSUE(k + 2, sn);               // stays in flight across barrier
    bf16x8 af[2], bfr[4];
#pragma unroll
    for (int t = 0; t < 2; ++t)
      af[t] = *reinterpret_cast<const bf16x8*>(&As[sc][(wm + t * 16 + l16) * BK + rsw]);
#pragma unroll
    for (int t = 0; t < 4; ++t)
      bfr[t] = *reinterpret_cast<const bf16x8*>(&Bs[sc][(t * 16 + l16) * BK + rsw]);
#pragma unroll
    for (int i = 0; i < 2; ++i)
#pragma unroll
      for (int j = 0; j < 4; ++j)
        acc[i][j] = __builtin_amdgcn_mfma_f32_16x16x32_bf16(af[i], bfr[j], acc[i][j], 0, 0, 0);
    if (k + 1 < NKi) {
      if (k + 2 < NKi) asm volatile("s_waitcnt vmcnt(3)" ::: "memory");  // tile k+1 done
      else             asm volatile("s_waitcnt vmcnt(0)" ::: "memory");
      __builtin_amdgcn_s_barrier();
    }
    sc = sc + 1; if (sc >= 3) sc = 0;
  }
#undef ISSUE
  asm volatile("s_waitcnt vmcnt(0)" ::: "memory");   // drain DMA before stores

  float* Pout = blockIdx.z ? Pout1 : Pout0;
  // epilogue: C/D layout col=lane&15, row=quad*4+reg
#pragma unroll
  for (int i = 0; i < 2; ++i)
#pragma unroll
    for (int j = 0; j < 4; ++j) {
      int col = n0 + j * 16 + l16;
      int rbase = m0 + wm + i * 16 + quad * 4;
      f32x4 v = acc[i][j];
#pragma unroll
      for (int r = 0; r < 4; ++r)
        Pout[(size_t)(rbase + r) * ldd + col] = v[r];
    }
}

// ---- 3: build_e2: sample-tiled E construction ------------------------------
// block b<400: sample n=b>>2, column-quarter q=b&3. Stage the sample's 10
// frame rows (summed Y0+Y1, left & right halves for this quarter) in LDS,
// then emit all 45 tuple rows; row norms via shuffle-reduce + atomicAdd.
// blocks 400..401: zero E pad rows 4500..4607.
__global__ __launch_bounds__(256)
void build_e2(const float* __restrict__ Y0, const float* __restrict__ Y1,
              const float* __restrict__ bias,
              unsigned short* __restrict__ E, float* __restrict__ sq) {
  int b = blockIdx.x, tid = threadIdx.x;
  if (b >= 400) {                       // zero pad rows
    const size_t base = (size_t)4500 * 2048 / 8;   // uint4 index
    const int total = 108 * 2048 / 8;              // 27648
    uint4 z = {0, 0, 0, 0};
    for (int i = (b - 400) * 256 + tid; i < total; i += 512)
      reinterpret_cast<uint4*>(E)[base + i] = z;
    return;
  }
  int n = b >> 2, q = b & 3;
  int c0 = q * 512;
  __shared__ float Lf[10][512];
  __shared__ float Rf[10][512];
  // stage: 10 frames x 512 cols x {left,right}, Y0+Y1 summed
  for (int e = tid; e < 1280; e += 256) {           // 1280 float4 slots per array
    int f  = e >> 7;                                // 128 float4 per frame
    int cc = (e & 127) << 2;
    const float* ya = Y0 + (size_t)(n * 10 + f) * 4096;
    const float* yb = Y1 + (size_t)(n * 10 + f) * 4096;
    float4 l0 = *reinterpret_cast<const float4*>(ya + c0 + cc);
    float4 l1 = *reinterpret_cast<const float4*>(yb + c0 + cc);
    float4 r0 = *reinterpret_cast<const float4*>(ya + 2048 + c0 + cc);
    float4 r1 = *reinterpret_cast<const float4*>(yb + 2048 + c0 + cc);
    float4 L = {l0.x + l1.x, l0.y + l1.y, l0.z + l1.z, l0.w + l1.w};
    float4 R = {r0.x + r1.x, r0.y + r1.y, r0.z + r1.z, r0.w + r1.w};
    *reinterpret_cast<float4*>(&Lf[f][cc]) = L;
    *reinterpret_cast<float4*>(&Rf[f][cc]) = R;
  }
  __syncthreads();
  int wv = tid >> 6, lane = tid & 63;
  int erow0 = (n < 75) ? n * 45 : NQT + (n - 75) * 45;
  for (int t = wv; t < 45; t += 4) {
    int f0 = P0[t], f1 = P1[t];
    int row = erow0 + t;
    float s = 0.f;
#pragma unroll
    for (int k = 0; k < 8; ++k) {
      int c = lane + 64 * k;                        // 0..511
      float x = Lf[f0][c] + Rf[f1][c] + bias[c0 + c];
      x = fmaxf(x, 0.f);
      unsigned short ob = f2b(x);
      E[(size_t)row * 2048 + c0 + c] = ob;
      float xr = b2f(ob);
      s += xr * xr;                                 // norm from rounded value
    }
#pragma unroll
    for (int sh = 32; sh > 0; sh >>= 1) s += __shfl_down(s, sh, 64);
    if (lane == 0) atomicAdd(&sq[row], s);
  }
}

// ---- 5: dist_stats: D from partials + per-class stats (fused) --------------
// 320 threads (5 waves). Step 1: D row from Pa+Pb (one float4/thread) ->
// global + LDS. Step 2 (query rows): wave w = class w stats from LDS.
__global__ __launch_bounds__(320)
void dist_stats(const float* __restrict__ Pa, const float* __restrict__ Pb,
                const float* __restrict__ sq, float* __restrict__ D,
                float* __restrict__ ave, int* __restrict__ pos,
                float* __restrict__ rmax) {
  __shared__ float drow[LDD];
  __shared__ float sm[5][64];
  int row = blockIdx.x, tid = threadIdx.x;
  float sr = sq[row];
  if (tid < 288) {                                   // 288 float4 = 1152 cols
    int c = tid * 4;
    size_t ix = (size_t)row * LDD / 4 + tid;
    float4 a = reinterpret_cast<const float4*>(Pa)[ix];
    float4 bb = reinterpret_cast<const float4*>(Pb)[ix];
    float4 o;
    o.x = sqrtf(fmaxf(sr + sq[NQT + c + 0] - 2.f * (a.x + bb.x), 0.f));
    o.y = sqrtf(fmaxf(sr + sq[NQT + c + 1] - 2.f * (a.y + bb.y), 0.f));
    o.z = sqrtf(fmaxf(sr + sq[NQT + c + 2] - 2.f * (a.z + bb.z), 0.f));
    o.w = sqrtf(fmaxf(sr + sq[NQT + c + 3] - 2.f * (a.w + bb.w), 0.f));
    reinterpret_cast<float4*>(D)[ix] = o;
    *reinterpret_cast<float4*>(&drow[c]) = o;
  }
  __syncthreads();
  if (row >= NQT) return;                            // support rows: D only
  int wv = tid >> 6, lane = tid & 63;                // wv = class 0..4
  const float* p = &drow[wv * 225];
  float best = -1e30f; int bi = 225;
  float gm = -1e30f;
  if (lane < 60) {
#pragma unroll
    for (int r = 0; r < 4; ++r) {
      int j = lane + 60 * r;
      if (j < 225) {
        float v = p[j];
        if (v > best) { best = v; bi = j; }          // first-occurrence (j asc)
        gm = fmaxf(gm, v);
      }
    }
  }
#pragma unroll
  for (int s = 32; s > 0; s >>= 1) {
    float vv = __shfl_down(best, s, 64);
    int   ii = __shfl_down(bi,   s, 64);
    if (vv > best || (vv == best && ii < bi)) { best = vv; bi = ii; }
  }
  sm[wv][lane] = gm;
  __builtin_amdgcn_wave_barrier();
  if (lane < 5) {
    float m = -1e30f;
#pragma unroll
    for (int a = 0; a < 12; ++a) m = fmaxf(m, sm[wv][lane + 5 * a]);
    sm[wv][lane] = m;
  }
  __builtin_amdgcn_wave_barrier();
  if (lane == 0) {
    float s5 = sm[wv][0] + sm[wv][1] + sm[wv][2] + sm[wv][3] + sm[wv][4];
    ave[wv * NQT + row]  = s5 * 0.2f;
    pos[wv * NQT + row]  = bi;
    rmax[wv * NQT + row] = best;
  }
}

// ---- 6a: record counts, 675 blocks (5 classes x 135 chunks of 25) ----------
__global__ void record_part(const float* __restrict__ D, const float* __restrict__ ave,
                            const int* __restrict__ pos, float* __restrict__ record) {
  int b = blockIdx.x;
  int c = b / 135, chunk = b - c * 135;
  int i0 = chunk * 25;
  int tid = threadIdx.x;
  __shared__ int   sp[25];
  __shared__ float sa[25];
  if (tid < 25) {
    sp[tid] = pos[c * NQT + i0 + tid];
    sa[tid] = ave[c * NQT + i0 + tid];
  }
  __syncthreads();
  float cnt[4] = {0.f, 0.f, 0.f, 0.f};
  int gcol[4];
#pragma unroll
  for (int j = 0; j < 4; ++j) {
    int col = tid + j * 256;
    gcol[j] = (col < 900) ? (col < c * 225 ? col : col + 225) : 0;
  }
  const bool act3 = (tid + 768) < 900;
  const float* Dsup = D + (size_t)(NQT + c * 225) * LDD;
  for (int ii = 0; ii < 25; ++ii) {
    const float* row = Dsup + (size_t)sp[ii] * LDD;
    float a = sa[ii];
    cnt[0] += (row[gcol[0]] > a) ? 1.f : 0.f;
    cnt[1] += (row[gcol[1]] > a) ? 1.f : 0.f;
    cnt[2] += (row[gcol[2]] > a) ? 1.f : 0.f;
    if (act3) cnt[3] += (row[gcol[3]] > a) ? 1.f : 0.f;
  }
#pragma unroll
  for (int j = 0; j < 4; ++j) {
    int col = tid + j * 256;
    if (col < 900) atomicAdd(&record[c * 900 + col], cnt[j]);
  }
}

// ---- 6b: thr + mask + msum partial ----------------------------------------
__global__ void record_finish(const float* __restrict__ record, float* __restrict__ mask,
                              float* __restrict__ msum) {
  int b = blockIdx.x;                 // 0..19
  int c = b / 4, mi = b - c * 4;
  int tid = threadIdx.x;
  float r = (tid < 225) ? record[c * 900 + mi * 225 + tid] : 0.f;
  __shared__ float s1[256], s2[256];
  __shared__ float thr_s;
  s1[tid] = r;
  s2[tid] = (tid < 225 && r != 0.f) ? 1.f : 0.f;
  __syncthreads();
  for (int st = 128; st > 0; st >>= 1) {
    if (tid < st) { s1[tid] += s1[tid + st]; s2[tid] += s2[tid + st]; }
    __syncthreads();
  }
  if (tid == 0) {
    float nz = s2[0] < 1.f ? 1.f : s2[0];
    thr_s = s1[0] / nz;
  }
  __syncthreads();
  float m = 0.f;
  if (tid < 225) {
    m = (r < thr_s) ? 1.f : 0.f;
    mask[(c * 4 + mi) * 225 + tid] = m;
  }
  s1[tid] = m;
  __syncthreads();
  for (int st = 128; st > 0; st >>= 1) {
    if (tid < st) s1[tid] += s1[tid + st];
    __syncthreads();
  }
  if (tid == 0) atomicAdd(&msum[c], s1[0]);
}

// ---- 7a: masked row dot products: S[c][i] = sum_col mask[c][col]*D[i,gcol] -
__global__ __launch_bounds__(256)
void contrast_rows(const float* __restrict__ D, const float* __restrict__ mask,
                   float* __restrict__ S) {
  int wave = threadIdx.x >> 6, lane = threadIdx.x & 63;
  int i = blockIdx.x * 4 + wave;
  int c = blockIdx.y;
  if (i >= NQT) return;
  const float* row = D + (size_t)i * LDD;
  const float* mk  = mask + c * 900;
  const int cbase = c * 225;
  float acc = 0.f;
#pragma unroll
  for (int k = 0; k < 15; ++k) {
    int col = k * 64 + lane;
    if (col < 900) {
      int gcol = col + (col >= cbase ? 225 : 0);
      acc += mk[col] * row[gcol];
    }
  }
#pragma unroll
  for (int s = 32; s > 0; s >>= 1) acc += __shfl_down(acc, s, 64);
  if (lane == 0) S[c * NQT + i] = acc;
}

// ---- 7b: final: dist_max + logits ------------------------------------------
__global__ void final_kernel(const float* __restrict__ S, const float* __restrict__ msum,
                             const float* __restrict__ rmax, float* __restrict__ out) {
  int gid = blockIdx.x * 256 + threadIdx.x;
  if (gid >= 375) return;
  int q = gid / 5, c = gid - q * 5;
  float dsum = 0.f, ssum = 0.f;
  for (int t = 0; t < 45; ++t) {
    dsum += rmax[c * NQT + q * 45 + t];
    ssum += S[c * NQT + q * 45 + t];
  }
  float dm = dsum / 45.f;
  float ms = msum[c]; if (ms < 1.f) ms = 1.f;
  float contrast = ssum / (ms * 180.f);   // /msum /45 /(WAY-1)
  out[q * 5 + c] = dm;
  out[375 + q * 5 + c] = dm / (contrast + dm);
}

// ---------------------------------------------------------------------------
extern "C" void kernel_launch(void* const* d_in, const int* in_sizes, int n_in,
                              void* d_out, int out_size, void* d_ws, size_t ws_size,
                              hipStream_t stream) {
  const float* support = (const float*)d_in[0];
  // d_in[1] = support_labels (arange//SHOT) -- class gather is a reshape, unused
  const float* queries = (const float*)d_in[2];
  const float* W       = (const float*)d_in[3];
  const float* bias    = (const float*)d_in[4];
  float* out = (float*)d_out;

  // Aliased workspace layout (lifetimes):
  //  [0, 21.2 MB):  Xb (4.2) + Ws (16.8)   -- dead after gemm1 --> reused as Pd1
  //  [21.2, 38.0):  Y0 (fp32 1024x4096)    -- dead after build_e2
  //  [38.0, 59.2):  Dm region: Y1 (16.8, dead after build_e2) -> Pd0 -> D
  //  [59.2, 78.1):  Eb (bf16 4608x2048)
  //  then smalls
  char* ws = (char*)d_ws;
  size_t off = 0;
  unsigned short* Xb  = (unsigned short*)(ws + off);
  unsigned short* Wsp = (unsigned short*)(ws + off + 4194304);
  float*          Pd1 = (float*)(ws + off);          off += 21233664;
  float*          Y0  = (float*)(ws + off);          off += (size_t)1024 * 4096 * 4;
  float*          Dm  = (float*)(ws + off);          // Pd0 / final D
  float*          Y1  = (float*)(ws + off);          off += (size_t)MPAD * LDD * 4;
  unsigned short* Eb  = (unsigned short*)(ws + off); off += (size_t)MPAD * 2048 * 2;
  float* sq      = (float*)(ws + off); off += 4608 * 4 + 256;
  float* ave     = (float*)(ws + off); off += 5 * NQT * 4 + 256;
  int*   pos     = (int*)(ws + off);   off += 5 * NQT * 4 + 256;
  float* rmax    = (float*)(ws + off); off += 5 * NQT * 4 + 256;
  float* mask    = (float*)(ws + off); off += 5 * 4 * 225 * 4 + 256;
  float* record  = (float*)(ws + off); off += 5 * 900 * 4 + 256;
  float* Sbuf    = (float*)(ws + off); off += 5 * NQT * 4 + 256;
  float* msum    = (float*)(ws + off); off += 5 * 4 + 256;

  prep<<<10276, 256, 0, stream>>>(W, queries, support, Wsp, Xb, record, msum, sq);

  dim3 g1(1024 / 128, 4096 / 64, 2);    // 8 x 64 x 2 = 1024 blocks, K=1024 each
  gemm_ring<<<g1, 256, 0, stream>>>(Xb, Wsp, 2048, 2048, 1024, Y0, Y1, 4096);

  build_e2<<<402, 256, 0, stream>>>(Y0, Y1, bias, Eb, sq);

  dim3 g2(MPAD / 128, LDD / 64, 2);     // 36 x 18 x 2 = 1296 blocks, K=1024 each
  gemm_ring<<<g2, 256, 0, stream>>>(Eb, Eb + (size_t)NQT * 2048, 2048, 2048, 1024,
                                    Dm, Pd1, LDD);

  dist_stats<<<MROWS, 320, 0, stream>>>(Dm, Pd1, sq, Dm, ave, pos, rmax);

  record_part<<<675, 256, 0, stream>>>(Dm, ave, pos, record);
  record_finish<<<20, 256, 0, stream>>>(record, mask, msum);
  dim3 gc((NQT + 3) / 4, 5);
  contrast_rows<<<gc, 256, 0, stream>>>(Dm, mask, Sbuf);
  final_kernel<<<2, 256, 0, stream>>>(Sbuf, msum, rmax, out);
}

// Round 12
// 232.010 us; speedup vs baseline: 1.0237x; 1.0237x over previous
//
#include <hip/hip_runtime.h>

// ---------------------------------------------------------------------------
// DistanceLoss pipeline on MI355X (gfx950)
//
// R4: tuple-gather factored out of embed GEMM (Y = X@Wsplit^T, 16.8 GFLOP).
// R5: contrast as per-(class,row) wave dot products.
// R9: split-K GEMMs, 3-stage global_load_lds ring, 128x128 tiles.
// R10: build_e2 sample-tiled; dist_fix+stats fused (dist_stats).
// R12: gemm2 split-K=4 (1296 blocks, staging traffic unchanged vs SK=2 —
//      split-K adds blocks without extra DMA, unlike smaller tiles which
//      regressed in R11). gemm1 stays SK=2.
//
//  1. prep: W fp32->split bf16; X bf16; zero record/msum/sq
//  2. gemm_ring grid(8,32,2):  Yz = X @ Wsplit^T (half-K partials, fp32)
//  3. build_e2: E rows (bf16) from Y0+Y1, sample-tiled; sq via atomics
//  4. gemm_ring grid(36,9,4):  Pz = E @ Esup^T (quarter-K partials)
//  5. dist_stats: D = sqrt(sq_r+sq_c-2*(P0+P1+P2+P3)) + per-(c,i) stats
//  6. record_part(675) / record_finish(+msum)
//  7. contrast_rows / final_kernel
// ---------------------------------------------------------------------------

typedef __bf16 bf16x8 __attribute__((ext_vector_type(8)));
typedef float f32x4 __attribute__((ext_vector_type(4)));

#define NQT   3375      // 75*45 query-tuple rows
#define MROWS 4500      // 3375 query rows + 1125 support rows
#define MPAD  4608      // 36 * 128
#define LDD   1152      // padded 1125 -> 9*128
#define BK    32        // K-tile; LDS stride = 32 (UNPADDED: required by global_load_lds)

__constant__ int P0[45] = {0,0,0,0,0,0,0,0,0,
                           1,1,1,1,1,1,1,1,
                           2,2,2,2,2,2,2,
                           3,3,3,3,3,3,
                           4,4,4,4,4,
                           5,5,5,5,
                           6,6,6,
                           7,7,
                           8};
__constant__ int P1[45] = {1,2,3,4,5,6,7,8,9,
                           2,3,4,5,6,7,8,9,
                           3,4,5,6,7,8,9,
                           4,5,6,7,8,9,
                           5,6,7,8,9,
                           6,7,8,9,
                           7,8,9,
                           8,9,
                           9};

__device__ inline unsigned short f2b(float x) {
  __bf16 b = (__bf16)x;               // RNE
  return __builtin_bit_cast(unsigned short, b);
}
__device__ inline float b2f(unsigned int u16) {
  return __uint_as_float(u16 << 16);
}

// async global->LDS, 16B per lane; lds dest must be wave-uniform base + lane*16
__device__ __forceinline__ void gl_lds16(const unsigned short* g, unsigned short* l) {
  __builtin_amdgcn_global_load_lds(
      (__attribute__((address_space(1))) void*)(g),
      (__attribute__((address_space(3))) void*)(l),
      16, 0, 0);
}

// ---- 1: prep: conv W (split) + conv X + zero record/msum/sq ----------------
__global__ void prep(const float* __restrict__ W, const float* __restrict__ Q,
                     const float* __restrict__ Sp,
                     unsigned short* __restrict__ Ws, unsigned short* __restrict__ X,
                     float* __restrict__ record, float* __restrict__ msum,
                     float* __restrict__ sq) {
  int b = blockIdx.x, tid = threadIdx.x;
  if (b < 8192) {                                    // W -> split bf16
    int i = b * 256 + tid;
    int i4 = i << 2;
    int o  = i4 >> 12;
    int k  = i4 & 4095;
    int hf = k >> 11;
    int kk = k & 2047;
    float4 v = reinterpret_cast<const float4*>(W)[i];
    ushort4 u;
    u.x = f2b(v.x); u.y = f2b(v.y); u.z = f2b(v.z); u.w = f2b(v.w);
    *reinterpret_cast<ushort4*>(Ws + (size_t)(o + hf * 2048) * 2048 + kk) = u;
  } else if (b < 10240) {                            // X = bf16(Q || S), pad 0
    int i = (b - 8192) * 256 + tid;
    ushort4 u = {0, 0, 0, 0};
    if (i < 384000) {                                // 750*2048/4
      float4 v = reinterpret_cast<const float4*>(Q)[i];
      u.x = f2b(v.x); u.y = f2b(v.y); u.z = f2b(v.z); u.w = f2b(v.w);
    } else if (i < 512000) {                         // + 250*2048/4
      float4 v = reinterpret_cast<const float4*>(Sp)[i - 384000];
      u.x = f2b(v.x); u.y = f2b(v.y); u.z = f2b(v.z); u.w = f2b(v.w);
    }
    reinterpret_cast<ushort4*>(X)[i] = u;
  } else {                                           // zero record + msum + sq
    int i = (b - 10240) * 256 + tid;
    if (i < 4500) record[i] = 0.f;
    else if (i < 4505) msum[i - 4500] = 0.f;
    else if (i < 4505 + 4608) sq[i - 4505] = 0.f;
  }
}

// ---- 2/4: bf16 MFMA GEMM, C = A @ B^T, 128x128 tile, BK=32, split-K --------
// 3-stage pipelined global_load_lds ring; chunk-XOR swizzle.
// blockIdx.z selects K-slice; raw fp32 accumulator partial stored to Pq[z].
__global__ __launch_bounds__(256)
void gemm_ring(const unsigned short* __restrict__ A, const unsigned short* __restrict__ B,
               int lda, int ldb, int Ksplit,
               float* __restrict__ Pq0, float* __restrict__ Pq1,
               float* __restrict__ Pq2, float* __restrict__ Pq3, int ldd) {
  __shared__ unsigned short As[3][128 * BK];   // 3 x 8 KB
  __shared__ unsigned short Bs[3][128 * BK];
  const int tid  = threadIdx.x;
  const int wave = tid >> 6, lane = tid & 63;
  const int quad = lane >> 4, l16 = lane & 15;
  const int wm = (wave >> 1) * 64, wn = (wave & 1) * 64;
  const int m0 = blockIdx.x * 128, n0 = blockIdx.y * 128;
  const int z  = blockIdx.z;
  const int kbase = z * Ksplit;

  f32x4 acc[4][4];
#pragma unroll
  for (int i = 0; i < 4; ++i)
#pragma unroll
    for (int j = 0; j < 4; ++j) {
      f32x4 zv = {0.f, 0.f, 0.f, 0.f};
      acc[i][j] = zv;
    }

  const int r0  = tid >> 2;                          // 0..63
  const int qsw = (tid & 3) ^ ((tid >> 3) & 3);      // swizzled global chunk
  const int kp0 = qsw * 8;
  const int rsw = (quad ^ ((l16 >> 1) & 3)) * 8;     // conflict-free read slot
  const unsigned short* pa0 = A + (size_t)(m0 + r0) * lda + kbase + kp0;
  const unsigned short* pa1 = A + (size_t)(m0 + r0 + 64) * lda + kbase + kp0;
  const unsigned short* pb0 = B + (size_t)(n0 + r0) * ldb + kbase + kp0;
  const unsigned short* pb1 = B + (size_t)(n0 + r0 + 64) * ldb + kbase + kp0;
  const int NKi = Ksplit / BK;

#define ISSUE(kk, st) do {                                   \
    gl_lds16(pa0 + (size_t)(kk) * BK, &As[st][wave * 512]);        \
    gl_lds16(pa1 + (size_t)(kk) * BK, &As[st][2048 + wave * 512]); \
    gl_lds16(pb0 + (size_t)(kk) * BK, &Bs[st][wave * 512]);        \
    gl_lds16(pb1 + (size_t)(kk) * BK, &Bs[st][2048 + wave * 512]); \
  } while (0)

  ISSUE(0, 0);
  ISSUE(1, 1);
  asm volatile("s_waitcnt vmcnt(4)" ::: "memory");   // tile 0 resident
  __builtin_amdgcn_s_barrier();

  int sc = 0;
  for (int k = 0; k < NKi; ++k) {
    int sn = sc + 2; if (sn >= 3) sn -= 3;
    if (k + 2 < NKi) ISSUE(k + 2, sn);               // stays in flight across barrier
    bf16x8 af[4], bfr[4];
#pragma unroll
    for (int t = 0; t < 4; ++t)
      af[t] = *reinterpret_cast<const bf16x8*>(&As[sc][(wm + t * 16 + l16) * BK + rsw]);
#pragma unroll
    for (int t = 0; t < 4; ++t)
      bfr[t] = *reinterpret_cast<const bf16x8*>(&Bs[sc][(wn + t * 16 + l16) * BK + rsw]);
#pragma unroll
    for (int i = 0; i < 4; ++i)
#pragma unroll
      for (int j = 0; j < 4; ++j)
        acc[i][j] = __builtin_amdgcn_mfma_f32_16x16x32_bf16(af[i], bfr[j], acc[i][j], 0, 0, 0);
    if (k + 1 < NKi) {
      if (k + 2 < NKi) asm volatile("s_waitcnt vmcnt(4)" ::: "memory");  // tile k+1 done
      else             asm volatile("s_waitcnt vmcnt(0)" ::: "memory");
      __builtin_amdgcn_s_barrier();
    }
    sc = sc + 1; if (sc >= 3) sc = 0;
  }
#undef ISSUE
  asm volatile("s_waitcnt vmcnt(0)" ::: "memory");   // drain DMA before stores

  float* Pout = (z == 0) ? Pq0 : (z == 1) ? Pq1 : (z == 2) ? Pq2 : Pq3;
  // epilogue: C/D layout col=lane&15, row=quad*4+reg
#pragma unroll
  for (int i = 0; i < 4; ++i)
#pragma unroll
    for (int j = 0; j < 4; ++j) {
      int col = n0 + wn + j * 16 + l16;
      int rbase = m0 + wm + i * 16 + quad * 4;
      f32x4 v = acc[i][j];
#pragma unroll
      for (int r = 0; r < 4; ++r)
        Pout[(size_t)(rbase + r) * ldd + col] = v[r];
    }
}

// ---- 3: build_e2: sample-tiled E construction ------------------------------
// block b<400: sample n=b>>2, column-quarter q=b&3. Stage the sample's 10
// frame rows (summed Y0+Y1, left & right halves for this quarter) in LDS,
// then emit all 45 tuple rows; row norms via shuffle-reduce + atomicAdd.
// blocks 400..401: zero E pad rows 4500..4607.
__global__ __launch_bounds__(256)
void build_e2(const float* __restrict__ Y0, const float* __restrict__ Y1,
              const float* __restrict__ bias,
              unsigned short* __restrict__ E, float* __restrict__ sq) {
  int b = blockIdx.x, tid = threadIdx.x;
  if (b >= 400) {                       // zero pad rows
    const size_t base = (size_t)4500 * 2048 / 8;   // uint4 index
    const int total = 108 * 2048 / 8;              // 27648
    uint4 z = {0, 0, 0, 0};
    for (int i = (b - 400) * 256 + tid; i < total; i += 512)
      reinterpret_cast<uint4*>(E)[base + i] = z;
    return;
  }
  int n = b >> 2, q = b & 3;
  int c0 = q * 512;
  __shared__ float Lf[10][512];
  __shared__ float Rf[10][512];
  // stage: 10 frames x 512 cols x {left,right}, Y0+Y1 summed
  for (int e = tid; e < 1280; e += 256) {           // 1280 float4 slots per array
    int f  = e >> 7;                                // 128 float4 per frame
    int cc = (e & 127) << 2;
    const float* ya = Y0 + (size_t)(n * 10 + f) * 4096;
    const float* yb = Y1 + (size_t)(n * 10 + f) * 4096;
    float4 l0 = *reinterpret_cast<const float4*>(ya + c0 + cc);
    float4 l1 = *reinterpret_cast<const float4*>(yb + c0 + cc);
    float4 r0 = *reinterpret_cast<const float4*>(ya + 2048 + c0 + cc);
    float4 r1 = *reinterpret_cast<const float4*>(yb + 2048 + c0 + cc);
    float4 L = {l0.x + l1.x, l0.y + l1.y, l0.z + l1.z, l0.w + l1.w};
    float4 R = {r0.x + r1.x, r0.y + r1.y, r0.z + r1.z, r0.w + r1.w};
    *reinterpret_cast<float4*>(&Lf[f][cc]) = L;
    *reinterpret_cast<float4*>(&Rf[f][cc]) = R;
  }
  __syncthreads();
  int wv = tid >> 6, lane = tid & 63;
  int erow0 = (n < 75) ? n * 45 : NQT + (n - 75) * 45;
  for (int t = wv; t < 45; t += 4) {
    int f0 = P0[t], f1 = P1[t];
    int row = erow0 + t;
    float s = 0.f;
#pragma unroll
    for (int k = 0; k < 8; ++k) {
      int c = lane + 64 * k;                        // 0..511
      float x = Lf[f0][c] + Rf[f1][c] + bias[c0 + c];
      x = fmaxf(x, 0.f);
      unsigned short ob = f2b(x);
      E[(size_t)row * 2048 + c0 + c] = ob;
      float xr = b2f(ob);
      s += xr * xr;                                 // norm from rounded value
    }
#pragma unroll
    for (int sh = 32; sh > 0; sh >>= 1) s += __shfl_down(s, sh, 64);
    if (lane == 0) atomicAdd(&sq[row], s);
  }
}

// ---- 5: dist_stats: D from 4 partials + per-class stats (fused) ------------
// 320 threads (5 waves). Step 1: D row from P0..P3 (one float4/thread) ->
// global + LDS. Step 2 (query rows): wave w = class w stats from LDS.
__global__ __launch_bounds__(320)
void dist_stats(const float* __restrict__ Pa, const float* __restrict__ Pb,
                const float* __restrict__ Pc, const float* __restrict__ Pd,
                const float* __restrict__ sq, float* __restrict__ D,
                float* __restrict__ ave, int* __restrict__ pos,
                float* __restrict__ rmax) {
  __shared__ float drow[LDD];
  __shared__ float sm[5][64];
  int row = blockIdx.x, tid = threadIdx.x;
  float sr = sq[row];
  if (tid < 288) {                                   // 288 float4 = 1152 cols
    int c = tid * 4;
    size_t ix = (size_t)row * LDD / 4 + tid;
    float4 a = reinterpret_cast<const float4*>(Pa)[ix];
    float4 b = reinterpret_cast<const float4*>(Pb)[ix];
    float4 e = reinterpret_cast<const float4*>(Pc)[ix];
    float4 f = reinterpret_cast<const float4*>(Pd)[ix];
    float sx = (a.x + b.x) + (e.x + f.x);
    float sy = (a.y + b.y) + (e.y + f.y);
    float sz = (a.z + b.z) + (e.z + f.z);
    float sw = (a.w + b.w) + (e.w + f.w);
    float4 o;
    o.x = sqrtf(fmaxf(sr + sq[NQT + c + 0] - 2.f * sx, 0.f));
    o.y = sqrtf(fmaxf(sr + sq[NQT + c + 1] - 2.f * sy, 0.f));
    o.z = sqrtf(fmaxf(sr + sq[NQT + c + 2] - 2.f * sz, 0.f));
    o.w = sqrtf(fmaxf(sr + sq[NQT + c + 3] - 2.f * sw, 0.f));
    reinterpret_cast<float4*>(D)[ix] = o;
    *reinterpret_cast<float4*>(&drow[c]) = o;
  }
  __syncthreads();
  if (row >= NQT) return;                            // support rows: D only
  int wv = tid >> 6, lane = tid & 63;                // wv = class 0..4
  const float* p = &drow[wv * 225];
  float best = -1e30f; int bi = 225;
  float gm = -1e30f;
  if (lane < 60) {
#pragma unroll
    for (int r = 0; r < 4; ++r) {
      int j = lane + 60 * r;
      if (j < 225) {
        float v = p[j];
        if (v > best) { best = v; bi = j; }          // first-occurrence (j asc)
        gm = fmaxf(gm, v);
      }
    }
  }
#pragma unroll
  for (int s = 32; s > 0; s >>= 1) {
    float vv = __shfl_down(best, s, 64);
    int   ii = __shfl_down(bi,   s, 64);
    if (vv > best || (vv == best && ii < bi)) { best = vv; bi = ii; }
  }
  sm[wv][lane] = gm;
  __builtin_amdgcn_wave_barrier();
  if (lane < 5) {
    float m = -1e30f;
#pragma unroll
    for (int a = 0; a < 12; ++a) m = fmaxf(m, sm[wv][lane + 5 * a]);
    sm[wv][lane] = m;
  }
  __builtin_amdgcn_wave_barrier();
  if (lane == 0) {
    float s5 = sm[wv][0] + sm[wv][1] + sm[wv][2] + sm[wv][3] + sm[wv][4];
    ave[wv * NQT + row]  = s5 * 0.2f;
    pos[wv * NQT + row]  = bi;
    rmax[wv * NQT + row] = best;
  }
}

// ---- 6a: record counts, 675 blocks (5 classes x 135 chunks of 25) ----------
__global__ void record_part(const float* __restrict__ D, const float* __restrict__ ave,
                            const int* __restrict__ pos, float* __restrict__ record) {
  int b = blockIdx.x;
  int c = b / 135, chunk = b - c * 135;
  int i0 = chunk * 25;
  int tid = threadIdx.x;
  __shared__ int   sp[25];
  __shared__ float sa[25];
  if (tid < 25) {
    sp[tid] = pos[c * NQT + i0 + tid];
    sa[tid] = ave[c * NQT + i0 + tid];
  }
  __syncthreads();
  float cnt[4] = {0.f, 0.f, 0.f, 0.f};
  int gcol[4];
#pragma unroll
  for (int j = 0; j < 4; ++j) {
    int col = tid + j * 256;
    gcol[j] = (col < 900) ? (col < c * 225 ? col : col + 225) : 0;
  }
  const bool act3 = (tid + 768) < 900;
  const float* Dsup = D + (size_t)(NQT + c * 225) * LDD;
  for (int ii = 0; ii < 25; ++ii) {
    const float* row = Dsup + (size_t)sp[ii] * LDD;
    float a = sa[ii];
    cnt[0] += (row[gcol[0]] > a) ? 1.f : 0.f;
    cnt[1] += (row[gcol[1]] > a) ? 1.f : 0.f;
    cnt[2] += (row[gcol[2]] > a) ? 1.f : 0.f;
    if (act3) cnt[3] += (row[gcol[3]] > a) ? 1.f : 0.f;
  }
#pragma unroll
  for (int j = 0; j < 4; ++j) {
    int col = tid + j * 256;
    if (col < 900) atomicAdd(&record[c * 900 + col], cnt[j]);
  }
}

// ---- 6b: thr + mask + msum partial ----------------------------------------
__global__ void record_finish(const float* __restrict__ record, float* __restrict__ mask,
                              float* __restrict__ msum) {
  int b = blockIdx.x;                 // 0..19
  int c = b / 4, mi = b - c * 4;
  int tid = threadIdx.x;
  float r = (tid < 225) ? record[c * 900 + mi * 225 + tid] : 0.f;
  __shared__ float s1[256], s2[256];
  __shared__ float thr_s;
  s1[tid] = r;
  s2[tid] = (tid < 225 && r != 0.f) ? 1.f : 0.f;
  __syncthreads();
  for (int st = 128; st > 0; st >>= 1) {
    if (tid < st) { s1[tid] += s1[tid + st]; s2[tid] += s2[tid + st]; }
    __syncthreads();
  }
  if (tid == 0) {
    float nz = s2[0] < 1.f ? 1.f : s2[0];
    thr_s = s1[0] / nz;
  }
  __syncthreads();
  float m = 0.f;
  if (tid < 225) {
    m = (r < thr_s) ? 1.f : 0.f;
    mask[(c * 4 + mi) * 225 + tid] = m;
  }
  s1[tid] = m;
  __syncthreads();
  for (int st = 128; st > 0; st >>= 1) {
    if (tid < st) s1[tid] += s1[tid + st];
    __syncthreads();
  }
  if (tid == 0) atomicAdd(&msum[c], s1[0]);
}

// ---- 7a: masked row dot products: S[c][i] = sum_col mask[c][col]*D[i,gcol] -
__global__ __launch_bounds__(256)
void contrast_rows(const float* __restrict__ D, const float* __restrict__ mask,
                   float* __restrict__ S) {
  int wave = threadIdx.x >> 6, lane = threadIdx.x & 63;
  int i = blockIdx.x * 4 + wave;
  int c = blockIdx.y;
  if (i >= NQT) return;
  const float* row = D + (size_t)i * LDD;
  const float* mk  = mask + c * 900;
  const int cbase = c * 225;
  float acc = 0.f;
#pragma unroll
  for (int k = 0; k < 15; ++k) {
    int col = k * 64 + lane;
    if (col < 900) {
      int gcol = col + (col >= cbase ? 225 : 0);
      acc += mk[col] * row[gcol];
    }
  }
#pragma unroll
  for (int s = 32; s > 0; s >>= 1) acc += __shfl_down(acc, s, 64);
  if (lane == 0) S[c * NQT + i] = acc;
}

// ---- 7b: final: dist_max + logits ------------------------------------------
__global__ void final_kernel(const float* __restrict__ S, const float* __restrict__ msum,
                             const float* __restrict__ rmax, float* __restrict__ out) {
  int gid = blockIdx.x * 256 + threadIdx.x;
  if (gid >= 375) return;
  int q = gid / 5, c = gid - q * 5;
  float dsum = 0.f, ssum = 0.f;
  for (int t = 0; t < 45; ++t) {
    dsum += rmax[c * NQT + q * 45 + t];
    ssum += S[c * NQT + q * 45 + t];
  }
  float dm = dsum / 45.f;
  float ms = msum[c]; if (ms < 1.f) ms = 1.f;
  float contrast = ssum / (ms * 180.f);   // /msum /45 /(WAY-1)
  out[q * 5 + c] = dm;
  out[375 + q * 5 + c] = dm / (contrast + dm);
}

// ---------------------------------------------------------------------------
extern "C" void kernel_launch(void* const* d_in, const int* in_sizes, int n_in,
                              void* d_out, int out_size, void* d_ws, size_t ws_size,
                              hipStream_t stream) {
  const float* support = (const float*)d_in[0];
  // d_in[1] = support_labels (arange//SHOT) -- class gather is a reshape, unused
  const float* queries = (const float*)d_in[2];
  const float* W       = (const float*)d_in[3];
  const float* bias    = (const float*)d_in[4];
  float* out = (float*)d_out;

  // Aliased workspace layout (ws = 268 MB per harness poison fill):
  //  [0, 21.2 MB):   Xb (4.2) + Ws (16.8)  -- dead after gemm1 --> reused as Pd1
  //  [21.2, 38.0):   Y0 (fp32 1024x4096)   -- dead after build_e2
  //  [38.0, 59.2):   Dm region: Y1 (dead after build_e2) -> Pd0 -> D
  //  [59.2, 78.1):   Eb (bf16 4608x2048)
  //  [78.1, ~79):    smalls
  //  [80.0, 101.2):  Pd2 (21.2 MB)
  //  [101.2, 122.4): Pd3 (21.2 MB)
  char* ws = (char*)d_ws;
  size_t off = 0;
  unsigned short* Xb  = (unsigned short*)(ws + off);
  unsigned short* Wsp = (unsigned short*)(ws + off + 4194304);
  float*          Pd1 = (float*)(ws + off);          off += 21233664;
  float*          Y0  = (float*)(ws + off);          off += (size_t)1024 * 4096 * 4;
  float*          Dm  = (float*)(ws + off);          // Pd0 / final D
  float*          Y1  = (float*)(ws + off);          off += (size_t)MPAD * LDD * 4;
  unsigned short* Eb  = (unsigned short*)(ws + off); off += (size_t)MPAD * 2048 * 2;
  float* sq      = (float*)(ws + off); off += 4608 * 4 + 256;
  float* ave     = (float*)(ws + off); off += 5 * NQT * 4 + 256;
  int*   pos     = (int*)(ws + off);   off += 5 * NQT * 4 + 256;
  float* rmax    = (float*)(ws + off); off += 5 * NQT * 4 + 256;
  float* mask    = (float*)(ws + off); off += 5 * 4 * 225 * 4 + 256;
  float* record  = (float*)(ws + off); off += 5 * 900 * 4 + 256;
  float* Sbuf    = (float*)(ws + off); off += 5 * NQT * 4 + 256;
  float* msum    = (float*)(ws + off); off += 5 * 4 + 256;
  float* Pd2     = (float*)(ws + 83886080);          // 80 MB
  float* Pd3     = (float*)(ws + 83886080 + 21233664);

  prep<<<10276, 256, 0, stream>>>(W, queries, support, Wsp, Xb, record, msum, sq);

  dim3 g1(1024 / 128, 4096 / 128, 2);   // 8 x 32 x 2 = 512 blocks, K=1024 each
  gemm_ring<<<g1, 256, 0, stream>>>(Xb, Wsp, 2048, 2048, 1024,
                                    Y0, Y1, Y0, Y0, 4096);

  build_e2<<<402, 256, 0, stream>>>(Y0, Y1, bias, Eb, sq);

  dim3 g2(MPAD / 128, LDD / 128, 4);    // 36 x 9 x 4 = 1296 blocks, K=512 each
  gemm_ring<<<g2, 256, 0, stream>>>(Eb, Eb + (size_t)NQT * 2048, 2048, 2048, 512,
                                    Dm, Pd1, Pd2, Pd3, LDD);

  dist_stats<<<MROWS, 320, 0, stream>>>(Dm, Pd1, Pd2, Pd3, sq, Dm, ave, pos, rmax);

  record_part<<<675, 256, 0, stream>>>(Dm, ave, pos, record);
  record_finish<<<20, 256, 0, stream>>>(record, mask, msum);
  dim3 gc((NQT + 3) / 4, 5);
  contrast_rows<<<gc, 256, 0, stream>>>(Dm, mask, Sbuf);
  final_kernel<<<2, 256, 0, stream>>>(Sbuf, msum, rmax, out);
}

// Round 14
// 220.727 us; speedup vs baseline: 1.0761x; 1.0511x over previous
//
#include <hip/hip_runtime.h>

// ---------------------------------------------------------------------------
// DistanceLoss pipeline on MI355X (gfx950)  — R14 = R10 (best verified: 222 us)
//
// R4: tuple-gather factored out of embed GEMM (Y = X@Wsplit^T, 16.8 GFLOP).
// R5: contrast as per-(class,row) wave dot products.
// R9: split-K=2 GEMMs (3-stage global_load_lds ring), 512/648 blocks.
// R10: build_e2 sample-tiled (Y read once, 40 KB LDS); dist_fix+stats fused.
// R11 (128x64 tiles), R12 (SK=4), R13 (cooperative tail) all measured worse
// or infeasible; reverted. This is the empirical local optimum.
//
//  1. prep: W fp32->split bf16; X bf16; zero record/msum/sq
//  2. gemm_ring grid(8,32,2):  Yz = X @ Wsplit^T (half-K partials, fp32)
//  3. build_e2: E rows (bf16) from Y0+Y1, sample-tiled; sq via atomics
//  4. gemm_ring grid(36,9,2):  Pz = E @ Esup^T (half-K partials)
//  5. dist_stats: D = sqrt(...), + per-(c,i) stats for query rows
//  6. record_part(675) / record_finish(+msum)
//  7. contrast_rows / final_kernel
// ---------------------------------------------------------------------------

typedef __bf16 bf16x8 __attribute__((ext_vector_type(8)));
typedef float f32x4 __attribute__((ext_vector_type(4)));

#define NQT   3375      // 75*45 query-tuple rows
#define MROWS 4500      // 3375 query rows + 1125 support rows
#define MPAD  4608      // 36 * 128
#define LDD   1152      // padded 1125 -> 9*128
#define BK    32        // K-tile; LDS stride = 32 (UNPADDED: required by global_load_lds)

__constant__ int P0[45] = {0,0,0,0,0,0,0,0,0,
                           1,1,1,1,1,1,1,1,
                           2,2,2,2,2,2,2,
                           3,3,3,3,3,3,
                           4,4,4,4,4,
                           5,5,5,5,
                           6,6,6,
                           7,7,
                           8};
__constant__ int P1[45] = {1,2,3,4,5,6,7,8,9,
                           2,3,4,5,6,7,8,9,
                           3,4,5,6,7,8,9,
                           4,5,6,7,8,9,
                           5,6,7,8,9,
                           6,7,8,9,
                           7,8,9,
                           8,9,
                           9};

__device__ inline unsigned short f2b(float x) {
  __bf16 b = (__bf16)x;               // RNE
  return __builtin_bit_cast(unsigned short, b);
}
__device__ inline float b2f(unsigned int u16) {
  return __uint_as_float(u16 << 16);
}

// async global->LDS, 16B per lane; lds dest must be wave-uniform base + lane*16
__device__ __forceinline__ void gl_lds16(const unsigned short* g, unsigned short* l) {
  __builtin_amdgcn_global_load_lds(
      (__attribute__((address_space(1))) void*)(g),
      (__attribute__((address_space(3))) void*)(l),
      16, 0, 0);
}

// ---- 1: prep: conv W (split) + conv X + zero record/msum/sq ----------------
__global__ void prep(const float* __restrict__ W, const float* __restrict__ Q,
                     const float* __restrict__ Sp,
                     unsigned short* __restrict__ Ws, unsigned short* __restrict__ X,
                     float* __restrict__ record, float* __restrict__ msum,
                     float* __restrict__ sq) {
  int b = blockIdx.x, tid = threadIdx.x;
  if (b < 8192) {                                    // W -> split bf16
    int i = b * 256 + tid;
    int i4 = i << 2;
    int o  = i4 >> 12;
    int k  = i4 & 4095;
    int hf = k >> 11;
    int kk = k & 2047;
    float4 v = reinterpret_cast<const float4*>(W)[i];
    ushort4 u;
    u.x = f2b(v.x); u.y = f2b(v.y); u.z = f2b(v.z); u.w = f2b(v.w);
    *reinterpret_cast<ushort4*>(Ws + (size_t)(o + hf * 2048) * 2048 + kk) = u;
  } else if (b < 10240) {                            // X = bf16(Q || S), pad 0
    int i = (b - 8192) * 256 + tid;
    ushort4 u = {0, 0, 0, 0};
    if (i < 384000) {                                // 750*2048/4
      float4 v = reinterpret_cast<const float4*>(Q)[i];
      u.x = f2b(v.x); u.y = f2b(v.y); u.z = f2b(v.z); u.w = f2b(v.w);
    } else if (i < 512000) {                         // + 250*2048/4
      float4 v = reinterpret_cast<const float4*>(Sp)[i - 384000];
      u.x = f2b(v.x); u.y = f2b(v.y); u.z = f2b(v.z); u.w = f2b(v.w);
    }
    reinterpret_cast<ushort4*>(X)[i] = u;
  } else {                                           // zero record + msum + sq
    int i = (b - 10240) * 256 + tid;
    if (i < 4500) record[i] = 0.f;
    else if (i < 4505) msum[i - 4500] = 0.f;
    else if (i < 4505 + 4608) sq[i - 4505] = 0.f;
  }
}

// ---- 2/4: bf16 MFMA GEMM, C = A @ B^T, 128x128 tile, BK=32, split-K --------
// 3-stage pipelined global_load_lds ring; chunk-XOR swizzle.
// blockIdx.z selects K-half; raw fp32 accumulator partial stored to Pz.
__global__ __launch_bounds__(256)
void gemm_ring(const unsigned short* __restrict__ A, const unsigned short* __restrict__ B,
               int lda, int ldb, int Ksplit,
               float* __restrict__ Pout0, float* __restrict__ Pout1, int ldd) {
  __shared__ unsigned short As[3][128 * BK];   // 3 x 8 KB
  __shared__ unsigned short Bs[3][128 * BK];
  const int tid  = threadIdx.x;
  const int wave = tid >> 6, lane = tid & 63;
  const int quad = lane >> 4, l16 = lane & 15;
  const int wm = (wave >> 1) * 64, wn = (wave & 1) * 64;
  const int m0 = blockIdx.x * 128, n0 = blockIdx.y * 128;
  const int kbase = blockIdx.z * Ksplit;

  f32x4 acc[4][4];
#pragma unroll
  for (int i = 0; i < 4; ++i)
#pragma unroll
    for (int j = 0; j < 4; ++j) {
      f32x4 z = {0.f, 0.f, 0.f, 0.f};
      acc[i][j] = z;
    }

  const int r0  = tid >> 2;                          // 0..63
  const int qsw = (tid & 3) ^ ((tid >> 3) & 3);      // swizzled global chunk
  const int kp0 = qsw * 8;
  const int rsw = (quad ^ ((l16 >> 1) & 3)) * 8;     // conflict-free read slot
  const unsigned short* pa0 = A + (size_t)(m0 + r0) * lda + kbase + kp0;
  const unsigned short* pa1 = A + (size_t)(m0 + r0 + 64) * lda + kbase + kp0;
  const unsigned short* pb0 = B + (size_t)(n0 + r0) * ldb + kbase + kp0;
  const unsigned short* pb1 = B + (size_t)(n0 + r0 + 64) * ldb + kbase + kp0;
  const int NKi = Ksplit / BK;

#define ISSUE(kk, st) do {                                   \
    gl_lds16(pa0 + (size_t)(kk) * BK, &As[st][wave * 512]);        \
    gl_lds16(pa1 + (size_t)(kk) * BK, &As[st][2048 + wave * 512]); \
    gl_lds16(pb0 + (size_t)(kk) * BK, &Bs[st][wave * 512]);        \
    gl_lds16(pb1 + (size_t)(kk) * BK, &Bs[st][2048 + wave * 512]); \
  } while (0)

  ISSUE(0, 0);
  ISSUE(1, 1);
  asm volatile("s_waitcnt vmcnt(4)" ::: "memory");   // tile 0 resident
  __builtin_amdgcn_s_barrier();

  int sc = 0;
  for (int k = 0; k < NKi; ++k) {
    int sn = sc + 2; if (sn >= 3) sn -= 3;
    if (k + 2 < NKi) ISSUE(k + 2, sn);               // stays in flight across barrier
    bf16x8 af[4], bfr[4];
#pragma unroll
    for (int t = 0; t < 4; ++t)
      af[t] = *reinterpret_cast<const bf16x8*>(&As[sc][(wm + t * 16 + l16) * BK + rsw]);
#pragma unroll
    for (int t = 0; t < 4; ++t)
      bfr[t] = *reinterpret_cast<const bf16x8*>(&Bs[sc][(wn + t * 16 + l16) * BK + rsw]);
#pragma unroll
    for (int i = 0; i < 4; ++i)
#pragma unroll
      for (int j = 0; j < 4; ++j)
        acc[i][j] = __builtin_amdgcn_mfma_f32_16x16x32_bf16(af[i], bfr[j], acc[i][j], 0, 0, 0);
    if (k + 1 < NKi) {
      if (k + 2 < NKi) asm volatile("s_waitcnt vmcnt(4)" ::: "memory");  // tile k+1 done
      else             asm volatile("s_waitcnt vmcnt(0)" ::: "memory");
      __builtin_amdgcn_s_barrier();
    }
    sc = sc + 1; if (sc >= 3) sc = 0;
  }
#undef ISSUE
  asm volatile("s_waitcnt vmcnt(0)" ::: "memory");   // drain DMA before stores

  float* Pout = blockIdx.z ? Pout1 : Pout0;
  // epilogue: C/D layout col=lane&15, row=quad*4+reg
#pragma unroll
  for (int i = 0; i < 4; ++i)
#pragma unroll
    for (int j = 0; j < 4; ++j) {
      int col = n0 + wn + j * 16 + l16;
      int rbase = m0 + wm + i * 16 + quad * 4;
      f32x4 v = acc[i][j];
#pragma unroll
      for (int r = 0; r < 4; ++r)
        Pout[(size_t)(rbase + r) * ldd + col] = v[r];
    }
}

// ---- 3: build_e2: sample-tiled E construction ------------------------------
// block b<400: sample n=b>>2, column-quarter q=b&3. Stage the sample's 10
// frame rows (summed Y0+Y1, left & right halves for this quarter) in LDS,
// then emit all 45 tuple rows; row norms via shuffle-reduce + atomicAdd.
// blocks 400..401: zero E pad rows 4500..4607.
__global__ __launch_bounds__(256)
void build_e2(const float* __restrict__ Y0, const float* __restrict__ Y1,
              const float* __restrict__ bias,
              unsigned short* __restrict__ E, float* __restrict__ sq) {
  int b = blockIdx.x, tid = threadIdx.x;
  if (b >= 400) {                       // zero pad rows
    const size_t base = (size_t)4500 * 2048 / 8;   // uint4 index
    const int total = 108 * 2048 / 8;              // 27648
    uint4 z = {0, 0, 0, 0};
    for (int i = (b - 400) * 256 + tid; i < total; i += 512)
      reinterpret_cast<uint4*>(E)[base + i] = z;
    return;
  }
  int n = b >> 2, q = b & 3;
  int c0 = q * 512;
  __shared__ float Lf[10][512];
  __shared__ float Rf[10][512];
  // stage: 10 frames x 512 cols x {left,right}, Y0+Y1 summed
  for (int e = tid; e < 1280; e += 256) {           // 1280 float4 slots per array
    int f  = e >> 7;                                // 128 float4 per frame
    int cc = (e & 127) << 2;
    const float* ya = Y0 + (size_t)(n * 10 + f) * 4096;
    const float* yb = Y1 + (size_t)(n * 10 + f) * 4096;
    float4 l0 = *reinterpret_cast<const float4*>(ya + c0 + cc);
    float4 l1 = *reinterpret_cast<const float4*>(yb + c0 + cc);
    float4 r0 = *reinterpret_cast<const float4*>(ya + 2048 + c0 + cc);
    float4 r1 = *reinterpret_cast<const float4*>(yb + 2048 + c0 + cc);
    float4 L = {l0.x + l1.x, l0.y + l1.y, l0.z + l1.z, l0.w + l1.w};
    float4 R = {r0.x + r1.x, r0.y + r1.y, r0.z + r1.z, r0.w + r1.w};
    *reinterpret_cast<float4*>(&Lf[f][cc]) = L;
    *reinterpret_cast<float4*>(&Rf[f][cc]) = R;
  }
  __syncthreads();
  int wv = tid >> 6, lane = tid & 63;
  int erow0 = (n < 75) ? n * 45 : NQT + (n - 75) * 45;
  for (int t = wv; t < 45; t += 4) {
    int f0 = P0[t], f1 = P1[t];
    int row = erow0 + t;
    float s = 0.f;
#pragma unroll
    for (int k = 0; k < 8; ++k) {
      int c = lane + 64 * k;                        // 0..511
      float x = Lf[f0][c] + Rf[f1][c] + bias[c0 + c];
      x = fmaxf(x, 0.f);
      unsigned short ob = f2b(x);
      E[(size_t)row * 2048 + c0 + c] = ob;
      float xr = b2f(ob);
      s += xr * xr;                                 // norm from rounded value
    }
#pragma unroll
    for (int sh = 32; sh > 0; sh >>= 1) s += __shfl_down(s, sh, 64);
    if (lane == 0) atomicAdd(&sq[row], s);
  }
}

// ---- 5: dist_stats: D from partials + per-class stats (fused) --------------
// 320 threads (5 waves). Step 1: D row from Pa+Pb (one float4/thread) ->
// global + LDS. Step 2 (query rows): wave w = class w stats from LDS.
__global__ __launch_bounds__(320)
void dist_stats(const float* __restrict__ Pa, const float* __restrict__ Pb,
                const float* __restrict__ sq, float* __restrict__ D,
                float* __restrict__ ave, int* __restrict__ pos,
                float* __restrict__ rmax) {
  __shared__ float drow[LDD];
  __shared__ float sm[5][64];
  int row = blockIdx.x, tid = threadIdx.x;
  float sr = sq[row];
  if (tid < 288) {                                   // 288 float4 = 1152 cols
    int c = tid * 4;
    size_t ix = (size_t)row * LDD / 4 + tid;
    float4 a = reinterpret_cast<const float4*>(Pa)[ix];
    float4 bb = reinterpret_cast<const float4*>(Pb)[ix];
    float4 o;
    o.x = sqrtf(fmaxf(sr + sq[NQT + c + 0] - 2.f * (a.x + bb.x), 0.f));
    o.y = sqrtf(fmaxf(sr + sq[NQT + c + 1] - 2.f * (a.y + bb.y), 0.f));
    o.z = sqrtf(fmaxf(sr + sq[NQT + c + 2] - 2.f * (a.z + bb.z), 0.f));
    o.w = sqrtf(fmaxf(sr + sq[NQT + c + 3] - 2.f * (a.w + bb.w), 0.f));
    reinterpret_cast<float4*>(D)[ix] = o;
    *reinterpret_cast<float4*>(&drow[c]) = o;
  }
  __syncthreads();
  if (row >= NQT) return;                            // support rows: D only
  int wv = tid >> 6, lane = tid & 63;                // wv = class 0..4
  const float* p = &drow[wv * 225];
  float best = -1e30f; int bi = 225;
  float gm = -1e30f;
  if (lane < 60) {
#pragma unroll
    for (int r = 0; r < 4; ++r) {
      int j = lane + 60 * r;
      if (j < 225) {
        float v = p[j];
        if (v > best) { best = v; bi = j; }          // first-occurrence (j asc)
        gm = fmaxf(gm, v);
      }
    }
  }
#pragma unroll
  for (int s = 32; s > 0; s >>= 1) {
    float vv = __shfl_down(best, s, 64);
    int   ii = __shfl_down(bi,   s, 64);
    if (vv > best || (vv == best && ii < bi)) { best = vv; bi = ii; }
  }
  sm[wv][lane] = gm;
  __builtin_amdgcn_wave_barrier();
  if (lane < 5) {
    float m = -1e30f;
#pragma unroll
    for (int a = 0; a < 12; ++a) m = fmaxf(m, sm[wv][lane + 5 * a]);
    sm[wv][lane] = m;
  }
  __builtin_amdgcn_wave_barrier();
  if (lane == 0) {
    float s5 = sm[wv][0] + sm[wv][1] + sm[wv][2] + sm[wv][3] + sm[wv][4];
    ave[wv * NQT + row]  = s5 * 0.2f;
    pos[wv * NQT + row]  = bi;
    rmax[wv * NQT + row] = best;
  }
}

// ---- 6a: record counts, 675 blocks (5 classes x 135 chunks of 25) ----------
__global__ void record_part(const float* __restrict__ D, const float* __restrict__ ave,
                            const int* __restrict__ pos, float* __restrict__ record) {
  int b = blockIdx.x;
  int c = b / 135, chunk = b - c * 135;
  int i0 = chunk * 25;
  int tid = threadIdx.x;
  __shared__ int   sp[25];
  __shared__ float sa[25];
  if (tid < 25) {
    sp[tid] = pos[c * NQT + i0 + tid];
    sa[tid] = ave[c * NQT + i0 + tid];
  }
  __syncthreads();
  float cnt[4] = {0.f, 0.f, 0.f, 0.f};
  int gcol[4];
#pragma unroll
  for (int j = 0; j < 4; ++j) {
    int col = tid + j * 256;
    gcol[j] = (col < 900) ? (col < c * 225 ? col : col + 225) : 0;
  }
  const bool act3 = (tid + 768) < 900;
  const float* Dsup = D + (size_t)(NQT + c * 225) * LDD;
  for (int ii = 0; ii < 25; ++ii) {
    const float* row = Dsup + (size_t)sp[ii] * LDD;
    float a = sa[ii];
    cnt[0] += (row[gcol[0]] > a) ? 1.f : 0.f;
    cnt[1] += (row[gcol[1]] > a) ? 1.f : 0.f;
    cnt[2] += (row[gcol[2]] > a) ? 1.f : 0.f;
    if (act3) cnt[3] += (row[gcol[3]] > a) ? 1.f : 0.f;
  }
#pragma unroll
  for (int j = 0; j < 4; ++j) {
    int col = tid + j * 256;
    if (col < 900) atomicAdd(&record[c * 900 + col], cnt[j]);
  }
}

// ---- 6b: thr + mask + msum partial ----------------------------------------
__global__ void record_finish(const float* __restrict__ record, float* __restrict__ mask,
                              float* __restrict__ msum) {
  int b = blockIdx.x;                 // 0..19
  int c = b / 4, mi = b - c * 4;
  int tid = threadIdx.x;
  float r = (tid < 225) ? record[c * 900 + mi * 225 + tid] : 0.f;
  __shared__ float s1[256], s2[256];
  __shared__ float thr_s;
  s1[tid] = r;
  s2[tid] = (tid < 225 && r != 0.f) ? 1.f : 0.f;
  __syncthreads();
  for (int st = 128; st > 0; st >>= 1) {
    if (tid < st) { s1[tid] += s1[tid + st]; s2[tid] += s2[tid + st]; }
    __syncthreads();
  }
  if (tid == 0) {
    float nz = s2[0] < 1.f ? 1.f : s2[0];
    thr_s = s1[0] / nz;
  }
  __syncthreads();
  float m = 0.f;
  if (tid < 225) {
    m = (r < thr_s) ? 1.f : 0.f;
    mask[(c * 4 + mi) * 225 + tid] = m;
  }
  s1[tid] = m;
  __syncthreads();
  for (int st = 128; st > 0; st >>= 1) {
    if (tid < st) s1[tid] += s1[tid + st];
    __syncthreads();
  }
  if (tid == 0) atomicAdd(&msum[c], s1[0]);
}

// ---- 7a: masked row dot products: S[c][i] = sum_col mask[c][col]*D[i,gcol] -
__global__ __launch_bounds__(256)
void contrast_rows(const float* __restrict__ D, const float* __restrict__ mask,
                   float* __restrict__ S) {
  int wave = threadIdx.x >> 6, lane = threadIdx.x & 63;
  int i = blockIdx.x * 4 + wave;
  int c = blockIdx.y;
  if (i >= NQT) return;
  const float* row = D + (size_t)i * LDD;
  const float* mk  = mask + c * 900;
  const int cbase = c * 225;
  float acc = 0.f;
#pragma unroll
  for (int k = 0; k < 15; ++k) {
    int col = k * 64 + lane;
    if (col < 900) {
      int gcol = col + (col >= cbase ? 225 : 0);
      acc += mk[col] * row[gcol];
    }
  }
#pragma unroll
  for (int s = 32; s > 0; s >>= 1) acc += __shfl_down(acc, s, 64);
  if (lane == 0) S[c * NQT + i] = acc;
}

// ---- 7b: final: dist_max + logits ------------------------------------------
__global__ void final_kernel(const float* __restrict__ S, const float* __restrict__ msum,
                             const float* __restrict__ rmax, float* __restrict__ out) {
  int gid = blockIdx.x * 256 + threadIdx.x;
  if (gid >= 375) return;
  int q = gid / 5, c = gid - q * 5;
  float dsum = 0.f, ssum = 0.f;
  for (int t = 0; t < 45; ++t) {
    dsum += rmax[c * NQT + q * 45 + t];
    ssum += S[c * NQT + q * 45 + t];
  }
  float dm = dsum / 45.f;
  float ms = msum[c]; if (ms < 1.f) ms = 1.f;
  float contrast = ssum / (ms * 180.f);   // /msum /45 /(WAY-1)
  out[q * 5 + c] = dm;
  out[375 + q * 5 + c] = dm / (contrast + dm);
}

// ---------------------------------------------------------------------------
extern "C" void kernel_launch(void* const* d_in, const int* in_sizes, int n_in,
                              void* d_out, int out_size, void* d_ws, size_t ws_size,
                              hipStream_t stream) {
  const float* support = (const float*)d_in[0];
  // d_in[1] = support_labels (arange//SHOT) -- class gather is a reshape, unused
  const float* queries = (const float*)d_in[2];
  const float* W       = (const float*)d_in[3];
  const float* bias    = (const float*)d_in[4];
  float* out = (float*)d_out;

  // Aliased workspace layout (lifetimes):
  //  [0, 21.2 MB):  Xb (4.2) + Ws (16.8)   -- dead after gemm1 --> reused as Pd1
  //  [21.2, 38.0):  Y0 (fp32 1024x4096)    -- dead after build_e2
  //  [38.0, 59.2):  Dm region: Y1 (dead after build_e2) -> Pd0 -> D
  //  [59.2, 78.1):  Eb (bf16 4608x2048)
  //  then smalls
  char* ws = (char*)d_ws;
  size_t off = 0;
  unsigned short* Xb  = (unsigned short*)(ws + off);
  unsigned short* Wsp = (unsigned short*)(ws + off + 4194304);
  float*          Pd1 = (float*)(ws + off);          off += 21233664;
  float*          Y0  = (float*)(ws + off);          off += (size_t)1024 * 4096 * 4;
  float*          Dm  = (float*)(ws + off);          // Pd0 / final D
  float*          Y1  = (float*)(ws + off);          off += (size_t)MPAD * LDD * 4;
  unsigned short* Eb  = (unsigned short*)(ws + off); off += (size_t)MPAD * 2048 * 2;
  float* sq      = (float*)(ws + off); off += 4608 * 4 + 256;
  float* ave     = (float*)(ws + off); off += 5 * NQT * 4 + 256;
  int*   pos     = (int*)(ws + off);   off += 5 * NQT * 4 + 256;
  float* rmax    = (float*)(ws + off); off += 5 * NQT * 4 + 256;
  float* mask    = (float*)(ws + off); off += 5 * 4 * 225 * 4 + 256;
  float* record  = (float*)(ws + off); off += 5 * 900 * 4 + 256;
  float* Sbuf    = (float*)(ws + off); off += 5 * NQT * 4 + 256;
  float* msum    = (float*)(ws + off); off += 5 * 4 + 256;

  prep<<<10276, 256, 0, stream>>>(W, queries, support, Wsp, Xb, record, msum, sq);

  dim3 g1(1024 / 128, 4096 / 128, 2);   // 8 x 32 x 2 = 512 blocks, K=1024 each
  gemm_ring<<<g1, 256, 0, stream>>>(Xb, Wsp, 2048, 2048, 1024, Y0, Y1, 4096);

  build_e2<<<402, 256, 0, stream>>>(Y0, Y1, bias, Eb, sq);

  dim3 g2(MPAD / 128, LDD / 128, 2);    // 36 x 9 x 2 = 648 blocks, K=1024 each
  gemm_ring<<<g2, 256, 0, stream>>>(Eb, Eb + (size_t)NQT * 2048, 2048, 2048, 1024,
                                    Dm, Pd1, LDD);

  dist_stats<<<MROWS, 320, 0, stream>>>(Dm, Pd1, sq, Dm, ave, pos, rmax);

  record_part<<<675, 256, 0, stream>>>(Dm, ave, pos, record);
  record_finish<<<20, 256, 0, stream>>>(record, mask, msum);
  dim3 gc((NQT + 3) / 4, 5);
  contrast_rows<<<gc, 256, 0, stream>>>(Dm, mask, Sbuf);
  final_kernel<<<2, 256, 0, stream>>>(Sbuf, msum, rmax, out);
}